// Round 9
// baseline (1899.124 us; speedup 1.0000x reference)
//
#include <hip/hip_runtime.h>
#include <math.h>

#define BATCH 4
#define CIN 64
#define HW 256
#define NPIX 65536       // 256*256
#define OC 192
#define TH 294
#define PS2 49
#define NWIN 36          // 6*6 windows per batch
#define WCPB 2304        // window-channels per batch (36*64)
#define C2N 2401         // 49*49 elements per window-channel
#define UPS 52           // padded row stride in upsampled tiles (208B, 16B-aligned)
#define KTSZ ((size_t)WCPB * PS2 * UPS)   // floats per tensor per batch (5,870,592)
#define KVPB (2 * KTSZ)                    // K+V floats per batch (46.97 MB)

// ---------------- K1: 1x1 conv (qkv) as LDS-tiled GEMM ----------------------
__global__ __launch_bounds__(256)
void k_qkv1x1(const float* __restrict__ x, const float* __restrict__ w,
              float* __restrict__ A) {
    __shared__ float wT[64][64];     // wT[c][o]
    __shared__ float xs[64][256];    // xs[c][px]
    x += (size_t)blockIdx.z * CIN * NPIX;
    A += (size_t)blockIdx.z * OC * NPIX;
    const int tid = threadIdx.x;
    const int pxbase = blockIdx.x * 256;
    const int ocbase = blockIdx.y * 64;

    for (int idx = tid; idx < 1024; idx += 256) {
        int o = idx >> 4, c4 = idx & 15;
        float4 v = *reinterpret_cast<const float4*>(w + (size_t)(ocbase + o) * CIN + c4 * 4);
        wT[c4 * 4 + 0][o] = v.x; wT[c4 * 4 + 1][o] = v.y;
        wT[c4 * 4 + 2][o] = v.z; wT[c4 * 4 + 3][o] = v.w;
    }
    for (int idx = tid; idx < 4096; idx += 256) {
        int c = idx >> 6, p4 = idx & 63;
        float4 v = *reinterpret_cast<const float4*>(x + (size_t)c * NPIX + pxbase + p4 * 4);
        *reinterpret_cast<float4*>(&xs[c][p4 * 4]) = v;
    }
    __syncthreads();

    const int tx = tid & 15, ty = tid >> 4;
    float acc[4][16];
    #pragma unroll
    for (int a = 0; a < 4; ++a)
        #pragma unroll
        for (int b = 0; b < 16; ++b) acc[a][b] = 0.f;

    #pragma unroll 4
    for (int k = 0; k < 64; ++k) {
        float4 wv = *reinterpret_cast<const float4*>(&wT[k][ty * 4]);
        float wr[4] = {wv.x, wv.y, wv.z, wv.w};
        float xv[16];
        #pragma unroll
        for (int i = 0; i < 4; ++i) {
            float4 v = *reinterpret_cast<const float4*>(&xs[k][tx * 4 + i * 64]);
            xv[i * 4 + 0] = v.x; xv[i * 4 + 1] = v.y;
            xv[i * 4 + 2] = v.z; xv[i * 4 + 3] = v.w;
        }
        #pragma unroll
        for (int a = 0; a < 4; ++a)
            #pragma unroll
            for (int b = 0; b < 16; ++b)
                acc[a][b] = fmaf(wr[a], xv[b], acc[a][b]);
    }

    #pragma unroll
    for (int a = 0; a < 4; ++a) {
        float* Ap = A + (size_t)(ocbase + ty * 4 + a) * NPIX + pxbase;
        #pragma unroll
        for (int i = 0; i < 4; ++i)
            *reinterpret_cast<float4*>(Ap + tx * 4 + i * 64) =
                make_float4(acc[a][i * 4 + 0], acc[a][i * 4 + 1],
                            acc[a][i * 4 + 2], acc[a][i * 4 + 3]);
    }
}

// ---------------- K2: depthwise 3x3, 4 pixels/thread ------------------------
__global__ __launch_bounds__(256)
void k_dw3x3(const float* __restrict__ A, const float* __restrict__ dwv,
             float* __restrict__ Bf) {
    A  += (size_t)blockIdx.z * OC * NPIX;
    Bf += (size_t)blockIdx.z * OC * NPIX;
    int gid = blockIdx.x * 256 + threadIdx.x;
    int ch = gid >> 14;
    int q  = gid & 16383;
    int y  = q >> 6;
    int x4 = (q & 63) << 2;
    const float* Ap = A + (size_t)ch * NPIX;
    float wv[9];
    #pragma unroll
    for (int i = 0; i < 9; ++i) wv[i] = dwv[ch * 9 + i];
    float acc0 = 0.f, acc1 = 0.f, acc2 = 0.f, acc3 = 0.f;
    #pragma unroll
    for (int ky = 0; ky < 3; ++ky) {
        int yy = y + ky - 1;
        if (yy < 0 || yy >= HW) continue;
        const float* row = Ap + yy * HW;
        float cv[6];
        #pragma unroll
        for (int t = 0; t < 6; ++t) {
            int xx = x4 - 1 + t;
            cv[t] = (xx >= 0 && xx < HW) ? row[xx] : 0.f;
        }
        #pragma unroll
        for (int kx = 0; kx < 3; ++kx) {
            float wk = wv[ky * 3 + kx];
            acc0 = fmaf(cv[0 + kx], wk, acc0);
            acc1 = fmaf(cv[1 + kx], wk, acc1);
            acc2 = fmaf(cv[2 + kx], wk, acc2);
            acc3 = fmaf(cv[3 + kx], wk, acc3);
        }
    }
    *reinterpret_cast<float4*>(Bf + (size_t)ch * NPIX + y * HW + x4) =
        make_float4(acc0, acc1, acc2, acc3);
}

// ---------------- K2.5: upsample K,V into window-matrix tiles ---------------
// KV[z][tensor y][wc][row i (pad 52)] = bilinear(B channel 64+64y+ch) at
// window-matrix position (i, t).  One block per (wc, tensor).
__global__ __launch_bounds__(256)
void k_up(const float* __restrict__ Bf, float* __restrict__ KV) {
    const int wc = blockIdx.x;
    const int ch = wc & 63, win = wc >> 6;
    const int xw = win / 6, yw = win - xw * 6;
    const float* src = Bf + (size_t)blockIdx.z * OC * NPIX
                          + (size_t)(64 + (blockIdx.y << 6) + ch) * NPIX;
    float* dst = KV + (size_t)blockIdx.z * KVPB + (size_t)blockIdx.y * KTSZ
                    + (size_t)wc * (PS2 * UPS);
    const float scale = 255.0f / 293.0f;       // align_corners=True, 256->294
    for (int e = threadIdx.x; e < C2N; e += 256) {
        int i = e / PS2, t = e - i * PS2;
        int rl = (t % 7) * 7 + (i % 7);
        int cl = (i / 7) * 7 + (t / 7);
        float sy = (float)(xw * PS2 + rl) * scale;
        float sx = (float)(yw * PS2 + cl) * scale;
        int y0 = (int)sy, x0 = (int)sx;
        float ly = sy - (float)y0, lx = sx - (float)x0;
        int y1 = min(y0 + 1, HW - 1), x1 = min(x0 + 1, HW - 1);
        const float* r0 = src + y0 * HW;
        const float* r1 = src + y1 * HW;
        float v = (r0[x0] * (1.f - lx) + r0[x1] * lx) * (1.f - ly)
                + (r1[x0] * (1.f - lx) + r1[x1] * lx) * ly;
        dst[i * UPS + t] = v;
    }
}

// ---------------- K3: fused attention, no LDS tiles, lane = query row -------
// K/V rows stream from the upsampled tiles as wave-uniform b128 broadcasts.
// |S|<=1 (cosine) => exp without max shift => single fused pass, o[49]+qreg[49].
__global__ __launch_bounds__(256, 3)
void k_attn(const float* __restrict__ Bf, const float* __restrict__ KV,
            float* __restrict__ C2) {
    __shared__ float inks[4][52];
    const int tid  = threadIdx.x;
    const int wvi  = tid >> 6, lane = tid & 63;
    const int wc   = blockIdx.x * 4 + wvi;      // [0, 2304)
    const int ch   = wc & 63;
    const int win  = wc >> 6;
    const int xw   = win / 6, yw = win - xw * 6;
    const float* qb = Bf + (size_t)blockIdx.z * OC * NPIX + (size_t)ch * NPIX;
    const float* Kt = KV + (size_t)blockIdx.z * KVPB + (size_t)wc * (PS2 * UPS);
    const float* Vt = Kt + KTSZ;
    C2 += (size_t)blockIdx.z * OC * NPIX;       // C2 region strides with B
    const float scale = 255.0f / 293.0f;
    const int l  = min(lane, PS2 - 1);          // matrix row i
    const int fr = l % 7, cc = l / 7;
    const bool act = (lane < PS2);

    // per-lane bilinear tables for Q row l (pixels: vert=(t%7)*7+fr, horz=cc*7+t/7)
    int   y0i[7], y1i[7], x0i[7], x1i[7];
    float lyf[7], lxf[7];
    #pragma unroll
    for (int a = 0; a < 7; ++a) {
        float sy = (float)(xw * PS2 + a * 7 + fr) * scale;
        int y0 = (int)sy;
        lyf[a] = sy - (float)y0;
        y0i[a] = y0 * HW;
        y1i[a] = min(y0 + 1, HW - 1) * HW;
        float sx = (float)(yw * PS2 + cc * 7 + a) * scale;
        int x0 = (int)sx;
        lxf[a] = sx - (float)x0;
        x0i[a] = x0;
        x1i[a] = min(x0 + 1, HW - 1);
    }

    // Q row -> registers, norm inline
    float qreg[PS2];
    float qss = 0.f;
    #pragma unroll
    for (int w_ = 0; w_ < 7; ++w_) {
        #pragma unroll
        for (int p_ = 0; p_ < 7; ++p_) {
            const int t = w_ * 7 + p_;
            int a00 = y0i[p_] + x0i[w_], a01 = y0i[p_] + x1i[w_];
            int a10 = y1i[p_] + x0i[w_], a11 = y1i[p_] + x1i[w_];
            float ly = lyf[p_], lx = lxf[w_];
            float w00 = (1.f - ly) * (1.f - lx), w01 = (1.f - ly) * lx;
            float w10 = ly * (1.f - lx),         w11 = ly * lx;
            float qv = qb[a00] * w00 + qb[a01] * w01 + qb[a10] * w10 + qb[a11] * w11;
            qreg[t] = qv;
            qss = fmaf(qv, qv, qss);
        }
    }
    float inq = 1.f / fmaxf(sqrtf(qss), 1e-12f);

    // K row l norm -> LDS (same-wave lockstep, no barrier)
    {
        const float* kr = Kt + l * UPS;
        float kss = 0.f;
        #pragma unroll
        for (int u = 0; u < 12; ++u) {
            float4 kk = *reinterpret_cast<const float4*>(&kr[u * 4]);
            kss = fmaf(kk.x, kk.x, kss);
            kss = fmaf(kk.y, kk.y, kss);
            kss = fmaf(kk.z, kk.z, kss);
            kss = fmaf(kk.w, kk.w, kss);
        }
        float k48 = kr[48];
        kss = fmaf(k48, k48, kss);
        if (act) inks[wvi][l] = 1.f / fmaxf(sqrtf(kss), 1e-12f);
    }

    // fused pass: p = exp(S), accumulate O and sum
    float o[PS2];
    #pragma unroll
    for (int t = 0; t < PS2; ++t) o[t] = 0.f;
    float ssum = 0.f;
    #pragma unroll 2
    for (int jj = 0; jj < PS2; ++jj) {
        const float* kr = Kt + jj * UPS;
        float d0 = 0.f, d1 = 0.f;
        #pragma unroll
        for (int u = 0; u < 12; ++u) {
            float4 kk = *reinterpret_cast<const float4*>(&kr[u * 4]);
            d0 = fmaf(qreg[u * 4 + 0], kk.x, d0);
            d1 = fmaf(qreg[u * 4 + 1], kk.y, d1);
            d0 = fmaf(qreg[u * 4 + 2], kk.z, d0);
            d1 = fmaf(qreg[u * 4 + 3], kk.w, d1);
        }
        d0 = fmaf(qreg[48], kr[48], d0);
        float p = __expf((d0 + d1) * inks[wvi][jj] * inq);
        ssum += p;
        const float* vr = Vt + jj * UPS;
        #pragma unroll
        for (int u = 0; u < 12; ++u) {
            float4 vv4 = *reinterpret_cast<const float4*>(&vr[u * 4]);
            o[u * 4 + 0] = fmaf(p, vv4.x, o[u * 4 + 0]);
            o[u * 4 + 1] = fmaf(p, vv4.y, o[u * 4 + 1]);
            o[u * 4 + 2] = fmaf(p, vv4.z, o[u * 4 + 2]);
            o[u * 4 + 3] = fmaf(p, vv4.w, o[u * 4 + 3]);
        }
        o[48] = fmaf(p, vr[48], o[48]);
    }
    float rs = 1.f / ssum;

    // store: C2[wc][t*49 + l] = O[l][t]  (consecutive lanes -> consecutive addr)
    float* cp = C2 + (size_t)wc * C2N;
    if (act) {
        #pragma unroll
        for (int t = 0; t < PS2; ++t)
            cp[t * PS2 + l] = o[t] * rs;
    }
}

// ------- K4: bilinear down 294->256 + proj, reading window-native C2 --------
// C2 holds O transposed: element (row i, col t) of window wc at wc*C2N + t*49 + i.
__device__ __forceinline__ int c2_base(int yy, int xx) {
    int xw = yy / PS2, rl = yy - xw * PS2;
    int yw = xx / PS2, cl = xx - yw * PS2;
    int i = (cl / 7) * 7 + rl % 7;      // matrix row
    int t = (cl % 7) * 7 + rl / 7;      // matrix col
    return ((xw * 6 + yw) * 64) * C2N + t * PS2 + i;
}

__global__ __launch_bounds__(256)
void k_proj(const float* __restrict__ C2, const float* __restrict__ pw,
            float* __restrict__ out) {
    C2  += (size_t)blockIdx.z * OC * NPIX;      // strides with B region
    out += (size_t)blockIdx.z * CIN * NPIX;
    int gid  = blockIdx.x * 256 + threadIdx.x;
    int half = gid >> 16;
    int p    = gid & 65535;
    int y = p >> 8, xx = p & 255;
    const float sc = 294.0f / 256.0f;
    float sy = fmaxf((y + 0.5f) * sc - 0.5f, 0.f);
    float sx = fmaxf((xx + 0.5f) * sc - 0.5f, 0.f);
    int y0 = (int)sy, x0 = (int)sx;
    float ly = sy - y0, lx = sx - x0;
    int y1 = min(y0 + 1, TH - 1), x1 = min(x0 + 1, TH - 1);
    float w00 = (1.f - ly) * (1.f - lx), w01 = (1.f - ly) * lx;
    float w10 = ly * (1.f - lx),         w11 = ly * lx;
    int b00 = c2_base(y0, x0), b01 = c2_base(y0, x1);
    int b10 = c2_base(y1, x0), b11 = c2_base(y1, x1);
    float rv[CIN];
    #pragma unroll
    for (int c = 0; c < CIN; ++c) {
        int co = c * C2N;
        rv[c] = C2[b00 + co] * w00 + C2[b01 + co] * w01 +
                C2[b10 + co] * w10 + C2[b11 + co] * w11;
    }
    float* op = out + (size_t)half * 32 * NPIX + p;
    for (int o = 0; o < 32; ++o) {
        const float* wr = pw + (half * 32 + o) * CIN;
        float acc = 0.f;
        #pragma unroll
        for (int c = 0; c < CIN; ++c) acc = fmaf(rv[c], wr[c], acc);
        op[(size_t)o * NPIX] = acc;
    }
}

// ---------------- launch --------------------------------------------------
// per-batch ws layout (96 MB):
//   [0, 47)   KV upsampled tiles (K then V), written by k_up over dead A
//   [48, 96)  B (q | k | v); after k_up, k-part+v-part are dead ->
//   [64, 86)  C2 = B + 64*NPIX  (attention output, window-native)
extern "C" void kernel_launch(void* const* d_in, const int* in_sizes, int n_in,
                              void* d_out, int out_size, void* d_ws, size_t ws_size,
                              hipStream_t stream) {
    const float* x   = (const float*)d_in[0];
    const float* qw  = (const float*)d_in[1];
    const float* dwv = (const float*)d_in[2];
    const float* pw  = (const float*)d_in[3];
    float* out = (float*)d_out;

    const size_t perAB = (size_t)OC * NPIX;
    const size_t needBig = (size_t)2 * BATCH * perAB * sizeof(float);  // 384 MB

    if (ws_size >= needBig) {
        float* A  = (float*)d_ws;
        float* B  = A + BATCH * perAB;       // z-stride perAB
        float* KV = A;                        // z-stride KVPB (fits: KVPB < perAB)
        float* C2 = B + (size_t)64 * NPIX;   // z-stride perAB
        hipLaunchKernelGGL(k_qkv1x1, dim3(256, 3, BATCH),   dim3(256), 0, stream, x, qw, A);
        hipLaunchKernelGGL(k_dw3x3,  dim3(12288, 1, BATCH), dim3(256), 0, stream, A, dwv, B);
        hipLaunchKernelGGL(k_up,     dim3(WCPB, 2, BATCH),  dim3(256), 0, stream, B, KV);
        hipLaunchKernelGGL(k_attn,   dim3(576, 1, BATCH),   dim3(256), 0, stream, B, KV, C2);
        hipLaunchKernelGGL(k_proj,   dim3(512, 1, BATCH),   dim3(256), 0, stream, C2, pw, out);
    } else {
        float* A  = (float*)d_ws;
        float* B  = A + perAB;
        float* KV = A;
        float* C2 = B + (size_t)64 * NPIX;
        for (int b = 0; b < BATCH; ++b) {
            const float* xb = x + (size_t)b * CIN * NPIX;
            float* ob = out + (size_t)b * CIN * NPIX;
            hipLaunchKernelGGL(k_qkv1x1, dim3(256, 3, 1),   dim3(256), 0, stream, xb, qw, A);
            hipLaunchKernelGGL(k_dw3x3,  dim3(12288, 1, 1), dim3(256), 0, stream, A, dwv, B);
            hipLaunchKernelGGL(k_up,     dim3(WCPB, 2, 1),  dim3(256), 0, stream, B, KV);
            hipLaunchKernelGGL(k_attn,   dim3(576, 1, 1),   dim3(256), 0, stream, B, KV, C2);
            hipLaunchKernelGGL(k_proj,   dim3(512, 1, 1),   dim3(256), 0, stream, C2, pw, ob);
        }
    }
}

// Round 10
// 1155.664 us; speedup vs baseline: 1.6433x; 1.6433x over previous
//
#include <hip/hip_runtime.h>
#include <math.h>

#define BATCH 4
#define CIN 64
#define HW 256
#define NPIX 65536       // 256*256
#define OC 192
#define TH 294
#define PS2 49
#define NWIN 36          // 6*6 windows per batch
#define WCPB 2304        // window-channels per batch (36*64)
#define C2N 2401         // 49*49 elements per window-channel
#define KSTR 52          // K-tile row stride (208B, 16B-aligned)
#define IOFF 2548        // ink[49] offset (floats)
#define VOFF 2600        // V row double-buffer offset (16B-aligned)
#define WVBUF 2704       // per-wave LDS floats (10816 B)

// ---------------- K1: 1x1 conv (qkv) as LDS-tiled GEMM ----------------------
__global__ __launch_bounds__(256)
void k_qkv1x1(const float* __restrict__ x, const float* __restrict__ w,
              float* __restrict__ A) {
    __shared__ float wT[64][64];     // wT[c][o]
    __shared__ float xs[64][256];    // xs[c][px]
    x += (size_t)blockIdx.z * CIN * NPIX;
    A += (size_t)blockIdx.z * OC * NPIX;
    const int tid = threadIdx.x;
    const int pxbase = blockIdx.x * 256;
    const int ocbase = blockIdx.y * 64;

    for (int idx = tid; idx < 1024; idx += 256) {
        int o = idx >> 4, c4 = idx & 15;
        float4 v = *reinterpret_cast<const float4*>(w + (size_t)(ocbase + o) * CIN + c4 * 4);
        wT[c4 * 4 + 0][o] = v.x; wT[c4 * 4 + 1][o] = v.y;
        wT[c4 * 4 + 2][o] = v.z; wT[c4 * 4 + 3][o] = v.w;
    }
    for (int idx = tid; idx < 4096; idx += 256) {
        int c = idx >> 6, p4 = idx & 63;
        float4 v = *reinterpret_cast<const float4*>(x + (size_t)c * NPIX + pxbase + p4 * 4);
        *reinterpret_cast<float4*>(&xs[c][p4 * 4]) = v;
    }
    __syncthreads();

    const int tx = tid & 15, ty = tid >> 4;
    float acc[4][16];
    #pragma unroll
    for (int a = 0; a < 4; ++a)
        #pragma unroll
        for (int b = 0; b < 16; ++b) acc[a][b] = 0.f;

    #pragma unroll 4
    for (int k = 0; k < 64; ++k) {
        float4 wv = *reinterpret_cast<const float4*>(&wT[k][ty * 4]);
        float wr[4] = {wv.x, wv.y, wv.z, wv.w};
        float xv[16];
        #pragma unroll
        for (int i = 0; i < 4; ++i) {
            float4 v = *reinterpret_cast<const float4*>(&xs[k][tx * 4 + i * 64]);
            xv[i * 4 + 0] = v.x; xv[i * 4 + 1] = v.y;
            xv[i * 4 + 2] = v.z; xv[i * 4 + 3] = v.w;
        }
        #pragma unroll
        for (int a = 0; a < 4; ++a)
            #pragma unroll
            for (int b = 0; b < 16; ++b)
                acc[a][b] = fmaf(wr[a], xv[b], acc[a][b]);
    }

    #pragma unroll
    for (int a = 0; a < 4; ++a) {
        float* Ap = A + (size_t)(ocbase + ty * 4 + a) * NPIX + pxbase;
        #pragma unroll
        for (int i = 0; i < 4; ++i)
            *reinterpret_cast<float4*>(Ap + tx * 4 + i * 64) =
                make_float4(acc[a][i * 4 + 0], acc[a][i * 4 + 1],
                            acc[a][i * 4 + 2], acc[a][i * 4 + 3]);
    }
}

// ---------------- K2: depthwise 3x3, 4 pixels/thread ------------------------
__global__ __launch_bounds__(256)
void k_dw3x3(const float* __restrict__ A, const float* __restrict__ dwv,
             float* __restrict__ Bf) {
    A  += (size_t)blockIdx.z * OC * NPIX;
    Bf += (size_t)blockIdx.z * OC * NPIX;
    int gid = blockIdx.x * 256 + threadIdx.x;
    int ch = gid >> 14;
    int q  = gid & 16383;
    int y  = q >> 6;
    int x4 = (q & 63) << 2;
    const float* Ap = A + (size_t)ch * NPIX;
    float wv[9];
    #pragma unroll
    for (int i = 0; i < 9; ++i) wv[i] = dwv[ch * 9 + i];
    float acc0 = 0.f, acc1 = 0.f, acc2 = 0.f, acc3 = 0.f;
    #pragma unroll
    for (int ky = 0; ky < 3; ++ky) {
        int yy = y + ky - 1;
        if (yy < 0 || yy >= HW) continue;
        const float* row = Ap + yy * HW;
        float cv[6];
        #pragma unroll
        for (int t = 0; t < 6; ++t) {
            int xx = x4 - 1 + t;
            cv[t] = (xx >= 0 && xx < HW) ? row[xx] : 0.f;
        }
        #pragma unroll
        for (int kx = 0; kx < 3; ++kx) {
            float wk = wv[ky * 3 + kx];
            acc0 = fmaf(cv[0 + kx], wk, acc0);
            acc1 = fmaf(cv[1 + kx], wk, acc1);
            acc2 = fmaf(cv[2 + kx], wk, acc2);
            acc3 = fmaf(cv[3 + kx], wk, acc3);
        }
    }
    *reinterpret_cast<float4*>(Bf + (size_t)ch * NPIX + y * HW + x4) =
        make_float4(acc0, acc1, acc2, acc3);
}

// ---------------- K3: fused attention; K tile in LDS, V row pipelined -------
// lane = query row; per jj: dot(Q,K[jj]) via b128 broadcast, exp (|S|<=1, no
// max shift), accumulate O from a 49-float V row that lane-as-element
// re-gathered one iteration ahead (double-buffered, same-wave -> no barrier).
__global__ __launch_bounds__(128)
void k_attn(const float* __restrict__ Bf, float* __restrict__ C2) {
    __shared__ float buf[2][WVBUF];
    Bf += (size_t)blockIdx.z * OC * NPIX;
    C2 += (size_t)blockIdx.z * (size_t)WCPB * C2N;
    const int tid  = threadIdx.x;
    const int wvi  = tid >> 6, lane = tid & 63;
    const int wc   = blockIdx.x * 2 + wvi;      // [0, 2304)
    const int ch   = wc & 63;
    const int win  = wc >> 6;
    const int xw   = win / 6, yw = win - xw * 6;
    const float* qb = Bf + (size_t)ch * NPIX;
    const float* kb = qb + (size_t)64  * NPIX;
    const float* vb = qb + (size_t)128 * NPIX;
    float* W = buf[wvi];
    const float scale = 255.0f / 293.0f;        // align_corners=True, 256->294
    const int l  = min(lane, PS2 - 1);
    const int fr = l % 7, cc = l / 7;
    const bool act = (lane < PS2);

    // tables for Q/K row-l gather (die after gather phase):
    // col t -> pixel vert=(t%7)*7+fr, horz=cc*7+(t/7)
    int   y0i[7], y1i[7], x0i[7], x1i[7];
    float lyf[7], lxf[7];
    #pragma unroll
    for (int a = 0; a < 7; ++a) {
        float sy = (float)(xw * PS2 + a * 7 + fr) * scale;
        int y0 = (int)sy;
        lyf[a] = sy - (float)y0;
        y0i[a] = y0 * HW;
        y1i[a] = min(y0 + 1, HW - 1) * HW;
        float sx = (float)(yw * PS2 + cc * 7 + a) * scale;
        int x0 = (int)sx;
        lxf[a] = sx - (float)x0;
        x0i[a] = x0;
        x1i[a] = min(x0 + 1, HW - 1);
    }

    // gather: Q row -> regs; K row -> LDS; norms inline
    float qreg[PS2];
    float qss = 0.f, kss = 0.f;
    #pragma unroll
    for (int w_ = 0; w_ < 7; ++w_) {
        #pragma unroll
        for (int p_ = 0; p_ < 7; ++p_) {
            const int t = w_ * 7 + p_;
            int a00 = y0i[p_] + x0i[w_], a01 = y0i[p_] + x1i[w_];
            int a10 = y1i[p_] + x0i[w_], a11 = y1i[p_] + x1i[w_];
            float ly = lyf[p_], lx = lxf[w_];
            float w00 = (1.f - ly) * (1.f - lx), w01 = (1.f - ly) * lx;
            float w10 = ly * (1.f - lx),         w11 = ly * lx;
            float qv = qb[a00] * w00 + qb[a01] * w01 + qb[a10] * w10 + qb[a11] * w11;
            float kv = kb[a00] * w00 + kb[a01] * w01 + kb[a10] * w10 + kb[a11] * w11;
            qreg[t] = qv;
            qss = fmaf(qv, qv, qss);
            kss = fmaf(kv, kv, kss);
            if (act) W[l * KSTR + t] = kv;
        }
    }
    float inq = 1.f / fmaxf(sqrtf(qss), 1e-12f);
    if (act) W[IOFF + l] = 1.f / fmaxf(sqrtf(kss), 1e-12f);   // ink[l]

    // V-row gather bases for lane as element e=l:
    // V[jj][l] -> pixel vert = fr*7 + jj%7, horz = (jj/7)*7 + cc
    const int baseVy = xw * PS2 + fr * 7;
    const int baseVx = yw * PS2 + cc;

    // prologue: V row 0 -> buffer 0 (jj=0 => jm=0, jd=0)
    {
        float sy = (float)baseVy * scale;
        int y0 = (int)sy;
        float gly = sy - (float)y0;
        int r0 = y0 * HW, r1 = min(y0 + 1, HW - 1) * HW;
        float sx = (float)baseVx * scale;
        int x0 = (int)sx;
        float glx = sx - (float)x0;
        int x1 = min(x0 + 1, HW - 1);
        float v = (vb[r0 + x0] * (1.f - glx) + vb[r0 + x1] * glx) * (1.f - gly)
                + (vb[r1 + x0] * (1.f - glx) + vb[r1 + x1] * glx) * gly;
        if (act) W[VOFF + l] = v;
    }

    float o[PS2];
    #pragma unroll
    for (int t = 0; t < PS2; ++t) o[t] = 0.f;
    float ssum = 0.f;
    int njm = 1, njd = 0;                       // (jj+1)%7, (jj+1)/7

    #pragma unroll 1
    for (int jj = 0; jj < PS2; ++jj) {
        // issue next V row's loads early (hide under this jj's FMAs)
        float g00 = 0.f, g01 = 0.f, g10 = 0.f, g11 = 0.f, gly = 0.f, glx = 0.f;
        const bool more = (jj < PS2 - 1);
        if (more) {
            float sy = (float)(baseVy + njm) * scale;
            int y0 = (int)sy;
            gly = sy - (float)y0;
            int r0 = y0 * HW, r1 = min(y0 + 1, HW - 1) * HW;
            float sx = (float)(baseVx + njd * 7) * scale;
            int x0 = (int)sx;
            glx = sx - (float)x0;
            int x1 = min(x0 + 1, HW - 1);
            g00 = vb[r0 + x0]; g01 = vb[r0 + x1];
            g10 = vb[r1 + x0]; g11 = vb[r1 + x1];
        }

        // dot(Q[lane], K[jj]) via uniform b128 broadcasts
        const float* kr = &W[jj * KSTR];
        float d0 = 0.f, d1 = 0.f, d2 = 0.f, d3 = 0.f;
        #pragma unroll
        for (int u = 0; u < 12; ++u) {
            float4 kk = *reinterpret_cast<const float4*>(&kr[u * 4]);
            d0 = fmaf(qreg[u * 4 + 0], kk.x, d0);
            d1 = fmaf(qreg[u * 4 + 1], kk.y, d1);
            d2 = fmaf(qreg[u * 4 + 2], kk.z, d2);
            d3 = fmaf(qreg[u * 4 + 3], kk.w, d3);
        }
        d0 = fmaf(qreg[48], kr[48], d0);
        float p = __expf(((d0 + d2) + (d1 + d3)) * W[IOFF + jj] * inq);
        ssum += p;

        // O += p * V[jj]  (broadcast from current row buffer)
        const float* vr = &W[VOFF + (jj & 1) * KSTR];
        #pragma unroll
        for (int u = 0; u < 12; ++u) {
            float4 vv4 = *reinterpret_cast<const float4*>(&vr[u * 4]);
            o[u * 4 + 0] = fmaf(p, vv4.x, o[u * 4 + 0]);
            o[u * 4 + 1] = fmaf(p, vv4.y, o[u * 4 + 1]);
            o[u * 4 + 2] = fmaf(p, vv4.z, o[u * 4 + 2]);
            o[u * 4 + 3] = fmaf(p, vv4.w, o[u * 4 + 3]);
        }
        o[48] = fmaf(p, vr[48], o[48]);

        // finish next row: interp + LDS write (other buffer)
        if (more) {
            float v = (g00 * (1.f - glx) + g01 * glx) * (1.f - gly)
                    + (g10 * (1.f - glx) + g11 * glx) * gly;
            if (act) W[VOFF + ((jj + 1) & 1) * KSTR + l] = v;
            if (++njm == 7) { njm = 0; ++njd; }
        }
    }
    float rs = 1.f / ssum;

    // store: C2[wc][t*49 + l] = O[l][t]  (consecutive lanes -> consecutive addr)
    float* cp = C2 + (size_t)wc * C2N;
    if (act) {
        #pragma unroll
        for (int t = 0; t < PS2; ++t)
            cp[t * PS2 + l] = o[t] * rs;
    }
}

// ------- K4: bilinear down 294->256 + proj, reading window-native C2 --------
// C2 holds O transposed: element (row i, col t) of window wc at wc*C2N + t*49 + i.
__device__ __forceinline__ int c2_base(int yy, int xx) {
    int xw = yy / PS2, rl = yy - xw * PS2;
    int yw = xx / PS2, cl = xx - yw * PS2;
    int i = (cl / 7) * 7 + rl % 7;      // matrix row
    int t = (cl % 7) * 7 + rl / 7;      // matrix col
    return ((xw * 6 + yw) * 64) * C2N + t * PS2 + i;
}

__global__ __launch_bounds__(256)
void k_proj(const float* __restrict__ C2, const float* __restrict__ pw,
            float* __restrict__ out) {
    C2  += (size_t)blockIdx.z * (size_t)WCPB * C2N;
    out += (size_t)blockIdx.z * CIN * NPIX;
    int gid  = blockIdx.x * 256 + threadIdx.x;
    int half = gid >> 16;
    int p    = gid & 65535;
    int y = p >> 8, xx = p & 255;
    const float sc = 294.0f / 256.0f;
    float sy = fmaxf((y + 0.5f) * sc - 0.5f, 0.f);
    float sx = fmaxf((xx + 0.5f) * sc - 0.5f, 0.f);
    int y0 = (int)sy, x0 = (int)sx;
    float ly = sy - y0, lx = sx - x0;
    int y1 = min(y0 + 1, TH - 1), x1 = min(x0 + 1, TH - 1);
    float w00 = (1.f - ly) * (1.f - lx), w01 = (1.f - ly) * lx;
    float w10 = ly * (1.f - lx),         w11 = ly * lx;
    int b00 = c2_base(y0, x0), b01 = c2_base(y0, x1);
    int b10 = c2_base(y1, x0), b11 = c2_base(y1, x1);
    float rv[CIN];
    #pragma unroll
    for (int c = 0; c < CIN; ++c) {
        int co = c * C2N;
        rv[c] = C2[b00 + co] * w00 + C2[b01 + co] * w01 +
                C2[b10 + co] * w10 + C2[b11 + co] * w11;
    }
    float* op = out + (size_t)half * 32 * NPIX + p;
    for (int o = 0; o < 32; ++o) {
        const float* wr = pw + (half * 32 + o) * CIN;
        float acc = 0.f;
        #pragma unroll
        for (int c = 0; c < CIN; ++c) acc = fmaf(rv[c], wr[c], acc);
        op[(size_t)o * NPIX] = acc;
    }
}

// ---------------- launch --------------------------------------------------
extern "C" void kernel_launch(void* const* d_in, const int* in_sizes, int n_in,
                              void* d_out, int out_size, void* d_ws, size_t ws_size,
                              hipStream_t stream) {
    const float* x   = (const float*)d_in[0];
    const float* qw  = (const float*)d_in[1];
    const float* dwv = (const float*)d_in[2];
    const float* pw  = (const float*)d_in[3];
    float* out = (float*)d_out;

    const size_t perAB = (size_t)OC * NPIX;
    const size_t needBig = (size_t)2 * BATCH * perAB * sizeof(float);  // 384 MB

    if (ws_size >= needBig) {
        float* A = (float*)d_ws;
        float* B = A + BATCH * perAB;
        float* C = A;   // C2 aliases A (dead after k_dw3x3); 22.1 MB/batch
        hipLaunchKernelGGL(k_qkv1x1, dim3(256, 3, BATCH),   dim3(256), 0, stream, x, qw, A);
        hipLaunchKernelGGL(k_dw3x3,  dim3(12288, 1, BATCH), dim3(256), 0, stream, A, dwv, B);
        hipLaunchKernelGGL(k_attn,   dim3(1152, 1, BATCH),  dim3(128), 0, stream, B, C);
        hipLaunchKernelGGL(k_proj,   dim3(512, 1, BATCH),   dim3(256), 0, stream, C, pw, out);
    } else {
        float* A = (float*)d_ws;
        float* B = A + perAB;
        float* C = A;
        for (int b = 0; b < BATCH; ++b) {
            const float* xb = x + (size_t)b * CIN * NPIX;
            float* ob = out + (size_t)b * CIN * NPIX;
            hipLaunchKernelGGL(k_qkv1x1, dim3(256, 3, 1),   dim3(256), 0, stream, xb, qw, A);
            hipLaunchKernelGGL(k_dw3x3,  dim3(12288, 1, 1), dim3(256), 0, stream, A, dwv, B);
            hipLaunchKernelGGL(k_attn,   dim3(1152, 1, 1),  dim3(128), 0, stream, B, C);
            hipLaunchKernelGGL(k_proj,   dim3(512, 1, 1),   dim3(256), 0, stream, C, pw, ob);
        }
    }
}

// Round 11
// 864.289 us; speedup vs baseline: 2.1973x; 1.3371x over previous
//
#include <hip/hip_runtime.h>
#include <math.h>

#define BATCH 4
#define CIN 64
#define HW 256
#define NPIX 65536       // 256*256
#define OC 192
#define TH 294
#define PS2 49
#define NWIN 36          // 6*6 windows per batch
#define WCPB 2304        // window-channels per batch (36*64)
#define C2N 2401         // 49*49 elements per window-channel
#define KSTR 52          // LDS row stride (208 B, 16B-aligned)

// ---------------- K1: 1x1 conv (qkv) as LDS-tiled GEMM ----------------------
__global__ __launch_bounds__(256)
void k_qkv1x1(const float* __restrict__ x, const float* __restrict__ w,
              float* __restrict__ A) {
    __shared__ float wT[64][64];     // wT[c][o]
    __shared__ float xs[64][256];    // xs[c][px]
    x += (size_t)blockIdx.z * CIN * NPIX;
    A += (size_t)blockIdx.z * OC * NPIX;
    const int tid = threadIdx.x;
    const int pxbase = blockIdx.x * 256;
    const int ocbase = blockIdx.y * 64;

    for (int idx = tid; idx < 1024; idx += 256) {
        int o = idx >> 4, c4 = idx & 15;
        float4 v = *reinterpret_cast<const float4*>(w + (size_t)(ocbase + o) * CIN + c4 * 4);
        wT[c4 * 4 + 0][o] = v.x; wT[c4 * 4 + 1][o] = v.y;
        wT[c4 * 4 + 2][o] = v.z; wT[c4 * 4 + 3][o] = v.w;
    }
    for (int idx = tid; idx < 4096; idx += 256) {
        int c = idx >> 6, p4 = idx & 63;
        float4 v = *reinterpret_cast<const float4*>(x + (size_t)c * NPIX + pxbase + p4 * 4);
        *reinterpret_cast<float4*>(&xs[c][p4 * 4]) = v;
    }
    __syncthreads();

    const int tx = tid & 15, ty = tid >> 4;
    float acc[4][16];
    #pragma unroll
    for (int a = 0; a < 4; ++a)
        #pragma unroll
        for (int b = 0; b < 16; ++b) acc[a][b] = 0.f;

    #pragma unroll 4
    for (int k = 0; k < 64; ++k) {
        float4 wv = *reinterpret_cast<const float4*>(&wT[k][ty * 4]);
        float wr[4] = {wv.x, wv.y, wv.z, wv.w};
        float xv[16];
        #pragma unroll
        for (int i = 0; i < 4; ++i) {
            float4 v = *reinterpret_cast<const float4*>(&xs[k][tx * 4 + i * 64]);
            xv[i * 4 + 0] = v.x; xv[i * 4 + 1] = v.y;
            xv[i * 4 + 2] = v.z; xv[i * 4 + 3] = v.w;
        }
        #pragma unroll
        for (int a = 0; a < 4; ++a)
            #pragma unroll
            for (int b = 0; b < 16; ++b)
                acc[a][b] = fmaf(wr[a], xv[b], acc[a][b]);
    }

    #pragma unroll
    for (int a = 0; a < 4; ++a) {
        float* Ap = A + (size_t)(ocbase + ty * 4 + a) * NPIX + pxbase;
        #pragma unroll
        for (int i = 0; i < 4; ++i)
            *reinterpret_cast<float4*>(Ap + tx * 4 + i * 64) =
                make_float4(acc[a][i * 4 + 0], acc[a][i * 4 + 1],
                            acc[a][i * 4 + 2], acc[a][i * 4 + 3]);
    }
}

// ---------------- K2: depthwise 3x3, 4 pixels/thread ------------------------
__global__ __launch_bounds__(256)
void k_dw3x3(const float* __restrict__ A, const float* __restrict__ dwv,
             float* __restrict__ Bf) {
    A  += (size_t)blockIdx.z * OC * NPIX;
    Bf += (size_t)blockIdx.z * OC * NPIX;
    int gid = blockIdx.x * 256 + threadIdx.x;
    int ch = gid >> 14;
    int q  = gid & 16383;
    int y  = q >> 6;
    int x4 = (q & 63) << 2;
    const float* Ap = A + (size_t)ch * NPIX;
    float wv[9];
    #pragma unroll
    for (int i = 0; i < 9; ++i) wv[i] = dwv[ch * 9 + i];
    float acc0 = 0.f, acc1 = 0.f, acc2 = 0.f, acc3 = 0.f;
    #pragma unroll
    for (int ky = 0; ky < 3; ++ky) {
        int yy = y + ky - 1;
        if (yy < 0 || yy >= HW) continue;
        const float* row = Ap + yy * HW;
        float cv[6];
        #pragma unroll
        for (int t = 0; t < 6; ++t) {
            int xx = x4 - 1 + t;
            cv[t] = (xx >= 0 && xx < HW) ? row[xx] : 0.f;
        }
        #pragma unroll
        for (int kx = 0; kx < 3; ++kx) {
            float wk = wv[ky * 3 + kx];
            acc0 = fmaf(cv[0 + kx], wk, acc0);
            acc1 = fmaf(cv[1 + kx], wk, acc1);
            acc2 = fmaf(cv[2 + kx], wk, acc2);
            acc3 = fmaf(cv[3 + kx], wk, acc3);
        }
    }
    *reinterpret_cast<float4*>(Bf + (size_t)ch * NPIX + y * HW + x4) =
        make_float4(acc0, acc1, acc2, acc3);
}

// ---------------- K3: block-per-wc attention, lane = column, zero shuffles --
// Lane l holds K row l (kreg) + V col l (vcol); per row i: dot via uniform
// Q-row b128 broadcasts, p = exp(S) (|S|<=1, no max shift), Ps same-wave LDS
// exchange, PV via uniform Ps broadcasts. ssum via ones-column (lane 49).
__global__ __launch_bounds__(256, 3)
void k_attn(const float* __restrict__ Bf, float* __restrict__ C2) {
    __shared__ float Qs[PS2 * KSTR];
    __shared__ float Ks[PS2 * KSTR];
    __shared__ float Vs[PS2 * KSTR];
    __shared__ float inqS[52];
    __shared__ float Ps[4][52];
    __shared__ float sums[52];
    Bf += (size_t)blockIdx.z * OC * NPIX;
    C2 += (size_t)blockIdx.z * (size_t)WCPB * C2N;
    const int tid = threadIdx.x;
    const int wv = tid >> 6, lane = tid & 63;
    const int wc  = blockIdx.x;                 // [0, 2304)
    const int ch  = wc & 63;
    const int win = wc >> 6;
    const int xw  = win / 6, yw = win - xw * 6;
    const float* qb = Bf + (size_t)ch * NPIX;
    const float* kb = qb + (size_t)64  * NPIX;
    const float* vb = qb + (size_t)128 * NPIX;
    const float scale = 255.0f / 293.0f;        // align_corners=True, 256->294

    // phase 1: bilinear gather into LDS with einops permutation
    for (int e = tid; e < PS2 * PS2; e += 256) {
        int rl = e / PS2;
        int cl = e - rl * PS2;
        int gy = xw * PS2 + rl, gx = yw * PS2 + cl;
        float sy = gy * scale, sx = gx * scale;
        int y0 = (int)sy, x0 = (int)sx;
        float ly = sy - y0, lx = sx - x0;
        int y1 = min(y0 + 1, HW - 1), x1 = min(x0 + 1, HW - 1);
        float w00 = (1.f - ly) * (1.f - lx), w01 = (1.f - ly) * lx;
        float w10 = ly * (1.f - lx),         w11 = ly * lx;
        int o00 = y0 * HW + x0, o01 = y0 * HW + x1;
        int o10 = y1 * HW + x0, o11 = y1 * HW + x1;
        int i = (cl / 7) * 7 + (rl % 7);
        int j = (cl % 7) * 7 + (rl / 7);
        int d = i * KSTR + j;
        Qs[d] = qb[o00] * w00 + qb[o01] * w01 + qb[o10] * w10 + qb[o11] * w11;
        Ks[d] = kb[o00] * w00 + kb[o01] * w01 + kb[o10] * w10 + kb[o11] * w11;
        Vs[d] = vb[o00] * w00 + vb[o01] * w01 + vb[o10] * w10 + vb[o11] * w11;
    }
    __syncthreads();

    const int l = min(lane, PS2 - 1);
    const bool act = (lane < PS2);

    // K row l -> registers; inverse norm stays lane-private
    float kreg[PS2];
    #pragma unroll
    for (int u = 0; u < 12; ++u) {
        float4 v = *reinterpret_cast<const float4*>(&Ks[l * KSTR + u * 4]);
        kreg[u * 4 + 0] = v.x; kreg[u * 4 + 1] = v.y;
        kreg[u * 4 + 2] = v.z; kreg[u * 4 + 3] = v.w;
    }
    kreg[48] = Ks[l * KSTR + 48];
    float kss = 0.f;
    #pragma unroll
    for (int t = 0; t < PS2; ++t) kss = fmaf(kreg[t], kreg[t], kss);
    const float inkl = 1.f / fmaxf(sqrtf(kss), 1e-12f);

    // V column l -> registers; lanes >= 49 get the ones-column (ssum trick)
    float vcol[PS2];
    #pragma unroll
    for (int jj = 0; jj < PS2; ++jj)
        vcol[jj] = act ? Vs[jj * KSTR + l] : 1.f;

    // Q row l inverse norm -> LDS (needed per-row by all lanes)
    {
        float qss = 0.f;
        #pragma unroll
        for (int u = 0; u < 12; ++u) {
            float4 v = *reinterpret_cast<const float4*>(&Qs[l * KSTR + u * 4]);
            qss = fmaf(v.x, v.x, qss); qss = fmaf(v.y, v.y, qss);
            qss = fmaf(v.z, v.z, qss); qss = fmaf(v.w, v.w, qss);
        }
        float q48 = Qs[l * KSTR + 48];
        qss = fmaf(q48, q48, qss);
        if (act) inqS[l] = 1.f / fmaxf(sqrtf(qss), 1e-12f);
    }
    __syncthreads();

    // row loop: wave wv owns rows i = wv, wv+4, ...
    for (int i = wv; i < PS2; i += 4) {
        const float inq_i = inqS[i];
        const float* qr = &Qs[i * KSTR];
        float d0 = 0.f, d1 = 0.f, d2 = 0.f, d3 = 0.f;
        #pragma unroll
        for (int u = 0; u < 12; ++u) {
            float4 qq = *reinterpret_cast<const float4*>(&qr[u * 4]);
            d0 = fmaf(qq.x, kreg[u * 4 + 0], d0);
            d1 = fmaf(qq.y, kreg[u * 4 + 1], d1);
            d2 = fmaf(qq.z, kreg[u * 4 + 2], d2);
            d3 = fmaf(qq.w, kreg[u * 4 + 3], d3);
        }
        d0 = fmaf(qr[48], kreg[48], d0);
        float p = __expf(((d0 + d1) + (d2 + d3)) * inkl * inq_i);
        if (act) Ps[wv][lane] = p;              // same-wave exchange, lockstep

        const float* pr = Ps[wv];
        float o0 = 0.f, o1 = 0.f, o2 = 0.f, o3 = 0.f;
        #pragma unroll
        for (int u = 0; u < 12; ++u) {
            float4 pp = *reinterpret_cast<const float4*>(&pr[u * 4]);
            o0 = fmaf(pp.x, vcol[u * 4 + 0], o0);
            o1 = fmaf(pp.y, vcol[u * 4 + 1], o1);
            o2 = fmaf(pp.z, vcol[u * 4 + 2], o2);
            o3 = fmaf(pp.w, vcol[u * 4 + 3], o3);
        }
        float ot = ((o0 + o1) + (o2 + o3)) + pr[48] * vcol[48];
        if (act) Qs[i * KSTR + lane] = ot;      // row i owned by this wave only
        if (lane == 49) sums[i] = ot;           // ones-column => ssum[i]
    }
    __syncthreads();
    if (tid < PS2) sums[tid] = 1.f / sums[tid];
    __syncthreads();

    // epilogue: C2[wc][t*49 + i] = O[i][t] / ssum[i]   (coalesced stores)
    float* cp = C2 + (size_t)wc * C2N;
    for (int e = tid; e < C2N; e += 256) {
        int t = e / PS2, i2 = e - t * PS2;
        cp[e] = Qs[i2 * KSTR + t] * sums[i2];
    }
}

// ------- K4: bilinear down 294->256 + proj, reading window-native C2 --------
// C2 holds O transposed: element (row i, col t) of window wc at wc*C2N + t*49 + i.
__device__ __forceinline__ int c2_base(int yy, int xx) {
    int xw = yy / PS2, rl = yy - xw * PS2;
    int yw = xx / PS2, cl = xx - yw * PS2;
    int i = (cl / 7) * 7 + rl % 7;      // matrix row
    int t = (cl % 7) * 7 + rl / 7;      // matrix col
    return ((xw * 6 + yw) * 64) * C2N + t * PS2 + i;
}

__global__ __launch_bounds__(256)
void k_proj(const float* __restrict__ C2, const float* __restrict__ pw,
            float* __restrict__ out) {
    C2  += (size_t)blockIdx.z * (size_t)WCPB * C2N;
    out += (size_t)blockIdx.z * CIN * NPIX;
    int gid  = blockIdx.x * 256 + threadIdx.x;
    int half = gid >> 16;
    int p    = gid & 65535;
    int y = p >> 8, xx = p & 255;
    const float sc = 294.0f / 256.0f;
    float sy = fmaxf((y + 0.5f) * sc - 0.5f, 0.f);
    float sx = fmaxf((xx + 0.5f) * sc - 0.5f, 0.f);
    int y0 = (int)sy, x0 = (int)sx;
    float ly = sy - y0, lx = sx - x0;
    int y1 = min(y0 + 1, TH - 1), x1 = min(x0 + 1, TH - 1);
    float w00 = (1.f - ly) * (1.f - lx), w01 = (1.f - ly) * lx;
    float w10 = ly * (1.f - lx),         w11 = ly * lx;
    int b00 = c2_base(y0, x0), b01 = c2_base(y0, x1);
    int b10 = c2_base(y1, x0), b11 = c2_base(y1, x1);
    float rv[CIN];
    #pragma unroll
    for (int c = 0; c < CIN; ++c) {
        int co = c * C2N;
        rv[c] = C2[b00 + co] * w00 + C2[b01 + co] * w01 +
                C2[b10 + co] * w10 + C2[b11 + co] * w11;
    }
    float* op = out + (size_t)half * 32 * NPIX + p;
    for (int o = 0; o < 32; ++o) {
        const float* wr = pw + (half * 32 + o) * CIN;
        float acc = 0.f;
        #pragma unroll
        for (int c = 0; c < CIN; ++c) acc = fmaf(rv[c], wr[c], acc);
        op[(size_t)o * NPIX] = acc;
    }
}

// ---------------- launch --------------------------------------------------
extern "C" void kernel_launch(void* const* d_in, const int* in_sizes, int n_in,
                              void* d_out, int out_size, void* d_ws, size_t ws_size,
                              hipStream_t stream) {
    const float* x   = (const float*)d_in[0];
    const float* qw  = (const float*)d_in[1];
    const float* dwv = (const float*)d_in[2];
    const float* pw  = (const float*)d_in[3];
    float* out = (float*)d_out;

    const size_t perAB = (size_t)OC * NPIX;
    const size_t needBig = (size_t)2 * BATCH * perAB * sizeof(float);  // 384 MB

    if (ws_size >= needBig) {
        float* A = (float*)d_ws;
        float* B = A + BATCH * perAB;
        float* C = A;   // C2 aliases A (dead after k_dw3x3); 22.1 MB/batch
        hipLaunchKernelGGL(k_qkv1x1, dim3(256, 3, BATCH),   dim3(256), 0, stream, x, qw, A);
        hipLaunchKernelGGL(k_dw3x3,  dim3(12288, 1, BATCH), dim3(256), 0, stream, A, dwv, B);
        hipLaunchKernelGGL(k_attn,   dim3(WCPB, 1, BATCH),  dim3(256), 0, stream, B, C);
        hipLaunchKernelGGL(k_proj,   dim3(512, 1, BATCH),   dim3(256), 0, stream, C, pw, out);
    } else {
        float* A = (float*)d_ws;
        float* B = A + perAB;
        float* C = A;
        for (int b = 0; b < BATCH; ++b) {
            const float* xb = x + (size_t)b * CIN * NPIX;
            float* ob = out + (size_t)b * CIN * NPIX;
            hipLaunchKernelGGL(k_qkv1x1, dim3(256, 3, 1),   dim3(256), 0, stream, xb, qw, A);
            hipLaunchKernelGGL(k_dw3x3,  dim3(12288, 1, 1), dim3(256), 0, stream, A, dwv, B);
            hipLaunchKernelGGL(k_attn,   dim3(WCPB, 1, 1),  dim3(256), 0, stream, B, C);
            hipLaunchKernelGGL(k_proj,   dim3(512, 1, 1),   dim3(256), 0, stream, C, pw, ob);
        }
    }
}

// Round 12
// 784.607 us; speedup vs baseline: 2.4205x; 1.1016x over previous
//
#include <hip/hip_runtime.h>
#include <math.h>

#define BATCH 4
#define CIN 64
#define HW 256
#define NPIX 65536       // 256*256
#define OC 192
#define TH 294
#define NPIX_R 86436     // 294*294
#define PS2 49
#define NWIN 36          // 6*6 windows per batch
#define WCPB 2304        // window-channels per batch (36*64)
#define KSTR 52          // LDS row stride (208 B, 16B-aligned)

// ---------------- K1: 1x1 conv (qkv) as LDS-tiled GEMM ----------------------
__global__ __launch_bounds__(256)
void k_qkv1x1(const float* __restrict__ x, const float* __restrict__ w,
              float* __restrict__ A) {
    __shared__ float wT[64][64];     // wT[c][o]
    __shared__ float xs[64][256];    // xs[c][px]
    x += (size_t)blockIdx.z * CIN * NPIX;
    A += (size_t)blockIdx.z * OC * NPIX;
    const int tid = threadIdx.x;
    const int pxbase = blockIdx.x * 256;
    const int ocbase = blockIdx.y * 64;

    for (int idx = tid; idx < 1024; idx += 256) {
        int o = idx >> 4, c4 = idx & 15;
        float4 v = *reinterpret_cast<const float4*>(w + (size_t)(ocbase + o) * CIN + c4 * 4);
        wT[c4 * 4 + 0][o] = v.x; wT[c4 * 4 + 1][o] = v.y;
        wT[c4 * 4 + 2][o] = v.z; wT[c4 * 4 + 3][o] = v.w;
    }
    for (int idx = tid; idx < 4096; idx += 256) {
        int c = idx >> 6, p4 = idx & 63;
        float4 v = *reinterpret_cast<const float4*>(x + (size_t)c * NPIX + pxbase + p4 * 4);
        *reinterpret_cast<float4*>(&xs[c][p4 * 4]) = v;
    }
    __syncthreads();

    const int tx = tid & 15, ty = tid >> 4;
    float acc[4][16];
    #pragma unroll
    for (int a = 0; a < 4; ++a)
        #pragma unroll
        for (int b = 0; b < 16; ++b) acc[a][b] = 0.f;

    #pragma unroll 4
    for (int k = 0; k < 64; ++k) {
        float4 wv = *reinterpret_cast<const float4*>(&wT[k][ty * 4]);
        float wr[4] = {wv.x, wv.y, wv.z, wv.w};
        float xv[16];
        #pragma unroll
        for (int i = 0; i < 4; ++i) {
            float4 v = *reinterpret_cast<const float4*>(&xs[k][tx * 4 + i * 64]);
            xv[i * 4 + 0] = v.x; xv[i * 4 + 1] = v.y;
            xv[i * 4 + 2] = v.z; xv[i * 4 + 3] = v.w;
        }
        #pragma unroll
        for (int a = 0; a < 4; ++a)
            #pragma unroll
            for (int b = 0; b < 16; ++b)
                acc[a][b] = fmaf(wr[a], xv[b], acc[a][b]);
    }

    #pragma unroll
    for (int a = 0; a < 4; ++a) {
        float* Ap = A + (size_t)(ocbase + ty * 4 + a) * NPIX + pxbase;
        #pragma unroll
        for (int i = 0; i < 4; ++i)
            *reinterpret_cast<float4*>(Ap + tx * 4 + i * 64) =
                make_float4(acc[a][i * 4 + 0], acc[a][i * 4 + 1],
                            acc[a][i * 4 + 2], acc[a][i * 4 + 3]);
    }
}

// ---------------- K2: depthwise 3x3, 4 pixels/thread ------------------------
__global__ __launch_bounds__(256)
void k_dw3x3(const float* __restrict__ A, const float* __restrict__ dwv,
             float* __restrict__ Bf) {
    A  += (size_t)blockIdx.z * OC * NPIX;
    Bf += (size_t)blockIdx.z * OC * NPIX;
    int gid = blockIdx.x * 256 + threadIdx.x;
    int ch = gid >> 14;
    int q  = gid & 16383;
    int y  = q >> 6;
    int x4 = (q & 63) << 2;
    const float* Ap = A + (size_t)ch * NPIX;
    float wv[9];
    #pragma unroll
    for (int i = 0; i < 9; ++i) wv[i] = dwv[ch * 9 + i];
    float acc0 = 0.f, acc1 = 0.f, acc2 = 0.f, acc3 = 0.f;
    #pragma unroll
    for (int ky = 0; ky < 3; ++ky) {
        int yy = y + ky - 1;
        if (yy < 0 || yy >= HW) continue;
        const float* row = Ap + yy * HW;
        float cv[6];
        #pragma unroll
        for (int t = 0; t < 6; ++t) {
            int xx = x4 - 1 + t;
            cv[t] = (xx >= 0 && xx < HW) ? row[xx] : 0.f;
        }
        #pragma unroll
        for (int kx = 0; kx < 3; ++kx) {
            float wk = wv[ky * 3 + kx];
            acc0 = fmaf(cv[0 + kx], wk, acc0);
            acc1 = fmaf(cv[1 + kx], wk, acc1);
            acc2 = fmaf(cv[2 + kx], wk, acc2);
            acc3 = fmaf(cv[3 + kx], wk, acc3);
        }
    }
    *reinterpret_cast<float4*>(Bf + (size_t)ch * NPIX + y * HW + x4) =
        make_float4(acc0, acc1, acc2, acc3);
}

// ---------------- K3: block-per-wc attention, lane = column, zero shuffles --
// Lane l holds K row l (kreg) + V col l (vcol); per row i: dot via uniform
// Q-row b128 broadcasts, p = exp(S) (|S|<=1, no max shift), Ps same-wave LDS
// exchange, PV via uniform Ps broadcasts. ssum via ones-column (lane 49).
// Epilogue: LDS-permute -> SPATIAL store (64,294,294) so k_proj reads coalesce.
__global__ __launch_bounds__(256, 3)
void k_attn(const float* __restrict__ Bf, float* __restrict__ Cf) {
    __shared__ float Qs[PS2 * KSTR];
    __shared__ float Ks[PS2 * KSTR];
    __shared__ float Vs[PS2 * KSTR];
    __shared__ float inqS[52];
    __shared__ float Ps[4][52];
    __shared__ float sums[52];
    Bf += (size_t)blockIdx.z * OC * NPIX;
    Cf += (size_t)blockIdx.z * (size_t)CIN * NPIX_R;
    const int tid = threadIdx.x;
    const int wv = tid >> 6, lane = tid & 63;
    const int wc  = blockIdx.x;                 // [0, 2304)
    const int ch  = wc & 63;
    const int win = wc >> 6;
    const int xw  = win / 6, yw = win - xw * 6;
    const float* qb = Bf + (size_t)ch * NPIX;
    const float* kb = qb + (size_t)64  * NPIX;
    const float* vb = qb + (size_t)128 * NPIX;
    const float scale = 255.0f / 293.0f;        // align_corners=True, 256->294

    // phase 1: bilinear gather into LDS with einops permutation
    for (int e = tid; e < PS2 * PS2; e += 256) {
        int rl = e / PS2;
        int cl = e - rl * PS2;
        int gy = xw * PS2 + rl, gx = yw * PS2 + cl;
        float sy = gy * scale, sx = gx * scale;
        int y0 = (int)sy, x0 = (int)sx;
        float ly = sy - y0, lx = sx - x0;
        int y1 = min(y0 + 1, HW - 1), x1 = min(x0 + 1, HW - 1);
        float w00 = (1.f - ly) * (1.f - lx), w01 = (1.f - ly) * lx;
        float w10 = ly * (1.f - lx),         w11 = ly * lx;
        int o00 = y0 * HW + x0, o01 = y0 * HW + x1;
        int o10 = y1 * HW + x0, o11 = y1 * HW + x1;
        int i = (cl / 7) * 7 + (rl % 7);
        int j = (cl % 7) * 7 + (rl / 7);
        int d = i * KSTR + j;
        Qs[d] = qb[o00] * w00 + qb[o01] * w01 + qb[o10] * w10 + qb[o11] * w11;
        Ks[d] = kb[o00] * w00 + kb[o01] * w01 + kb[o10] * w10 + kb[o11] * w11;
        Vs[d] = vb[o00] * w00 + vb[o01] * w01 + vb[o10] * w10 + vb[o11] * w11;
    }
    __syncthreads();

    const int l = min(lane, PS2 - 1);
    const bool act = (lane < PS2);

    // K row l -> registers; inverse norm stays lane-private
    float kreg[PS2];
    #pragma unroll
    for (int u = 0; u < 12; ++u) {
        float4 v = *reinterpret_cast<const float4*>(&Ks[l * KSTR + u * 4]);
        kreg[u * 4 + 0] = v.x; kreg[u * 4 + 1] = v.y;
        kreg[u * 4 + 2] = v.z; kreg[u * 4 + 3] = v.w;
    }
    kreg[48] = Ks[l * KSTR + 48];
    float kss = 0.f;
    #pragma unroll
    for (int t = 0; t < PS2; ++t) kss = fmaf(kreg[t], kreg[t], kss);
    const float inkl = 1.f / fmaxf(sqrtf(kss), 1e-12f);

    // V column l -> registers; lanes >= 49 get the ones-column (ssum trick)
    float vcol[PS2];
    #pragma unroll
    for (int jj = 0; jj < PS2; ++jj)
        vcol[jj] = act ? Vs[jj * KSTR + l] : 1.f;

    // Q row l inverse norm -> LDS (needed per-row by all lanes)
    {
        float qss = 0.f;
        #pragma unroll
        for (int u = 0; u < 12; ++u) {
            float4 v = *reinterpret_cast<const float4*>(&Qs[l * KSTR + u * 4]);
            qss = fmaf(v.x, v.x, qss); qss = fmaf(v.y, v.y, qss);
            qss = fmaf(v.z, v.z, qss); qss = fmaf(v.w, v.w, qss);
        }
        float q48 = Qs[l * KSTR + 48];
        qss = fmaf(q48, q48, qss);
        if (act) inqS[l] = 1.f / fmaxf(sqrtf(qss), 1e-12f);
    }
    __syncthreads();

    // row loop: wave wv owns rows i = wv, wv+4, ...
    for (int i = wv; i < PS2; i += 4) {
        const float inq_i = inqS[i];
        const float* qr = &Qs[i * KSTR];
        float d0 = 0.f, d1 = 0.f, d2 = 0.f, d3 = 0.f;
        #pragma unroll
        for (int u = 0; u < 12; ++u) {
            float4 qq = *reinterpret_cast<const float4*>(&qr[u * 4]);
            d0 = fmaf(qq.x, kreg[u * 4 + 0], d0);
            d1 = fmaf(qq.y, kreg[u * 4 + 1], d1);
            d2 = fmaf(qq.z, kreg[u * 4 + 2], d2);
            d3 = fmaf(qq.w, kreg[u * 4 + 3], d3);
        }
        d0 = fmaf(qr[48], kreg[48], d0);
        float p = __expf(((d0 + d1) + (d2 + d3)) * inkl * inq_i);
        if (act) Ps[wv][lane] = p;              // same-wave exchange, lockstep

        const float* pr = Ps[wv];
        float o0 = 0.f, o1 = 0.f, o2 = 0.f, o3 = 0.f;
        #pragma unroll
        for (int u = 0; u < 12; ++u) {
            float4 pp = *reinterpret_cast<const float4*>(&pr[u * 4]);
            o0 = fmaf(pp.x, vcol[u * 4 + 0], o0);
            o1 = fmaf(pp.y, vcol[u * 4 + 1], o1);
            o2 = fmaf(pp.z, vcol[u * 4 + 2], o2);
            o3 = fmaf(pp.w, vcol[u * 4 + 3], o3);
        }
        float ot = ((o0 + o1) + (o2 + o3)) + pr[48] * vcol[48];
        if (act) Qs[i * KSTR + lane] = ot;      // row i owned by this wave only
        if (lane == 49) sums[i] = ot;           // ones-column => ssum[i]
    }
    __syncthreads();
    if (tid < PS2) sums[tid] = 1.f / sums[tid];
    __syncthreads();

    // epilogue: inverse window permutation via LDS -> spatial C (64,294,294);
    // consecutive e -> consecutive gx => coalesced 49-float runs.
    float* cb = Cf + (size_t)ch * NPIX_R;
    for (int e = tid; e < PS2 * PS2; e += 256) {
        int rl = e / PS2;
        int cl = e - rl * PS2;
        int i = (cl / 7) * 7 + (rl % 7);
        int j = (cl % 7) * 7 + (rl / 7);
        cb[(xw * PS2 + rl) * TH + (yw * PS2 + cl)] = Qs[i * KSTR + j] * sums[i];
    }
}

// ------- K4: bilinear down 294->256 + proj, reading SPATIAL C ---------------
__global__ __launch_bounds__(256)
void k_proj(const float* __restrict__ Cf, const float* __restrict__ pw,
            float* __restrict__ out) {
    Cf  += (size_t)blockIdx.z * (size_t)CIN * NPIX_R;
    out += (size_t)blockIdx.z * CIN * NPIX;
    int gid  = blockIdx.x * 256 + threadIdx.x;
    int half = gid >> 16;
    int p    = gid & 65535;
    int y = p >> 8, xx = p & 255;
    const float sc = 294.0f / 256.0f;
    float sy = fmaxf((y + 0.5f) * sc - 0.5f, 0.f);
    float sx = fmaxf((xx + 0.5f) * sc - 0.5f, 0.f);
    int y0 = (int)sy, x0 = (int)sx;
    float ly = sy - y0, lx = sx - x0;
    int y1 = min(y0 + 1, TH - 1), x1 = min(x0 + 1, TH - 1);
    float w00 = (1.f - ly) * (1.f - lx), w01 = (1.f - ly) * lx;
    float w10 = ly * (1.f - lx),         w11 = ly * lx;
    int o00 = y0 * TH + x0, o01 = y0 * TH + x1;
    int o10 = y1 * TH + x0, o11 = y1 * TH + x1;
    float rv[CIN];
    #pragma unroll
    for (int c = 0; c < CIN; ++c) {
        const float* cp = Cf + (size_t)c * NPIX_R;
        rv[c] = cp[o00] * w00 + cp[o01] * w01 + cp[o10] * w10 + cp[o11] * w11;
    }
    float* op = out + (size_t)half * 32 * NPIX + p;
    for (int o = 0; o < 32; ++o) {
        const float* wr = pw + (half * 32 + o) * CIN;
        float acc = 0.f;
        #pragma unroll
        for (int c = 0; c < CIN; ++c) acc = fmaf(rv[c], wr[c], acc);
        op[(size_t)o * NPIX] = acc;
    }
}

// ---------------- launch --------------------------------------------------
extern "C" void kernel_launch(void* const* d_in, const int* in_sizes, int n_in,
                              void* d_out, int out_size, void* d_ws, size_t ws_size,
                              hipStream_t stream) {
    const float* x   = (const float*)d_in[0];
    const float* qw  = (const float*)d_in[1];
    const float* dwv = (const float*)d_in[2];
    const float* pw  = (const float*)d_in[3];
    float* out = (float*)d_out;

    const size_t perAB = (size_t)OC * NPIX;
    const size_t needBig = (size_t)2 * BATCH * perAB * sizeof(float);  // 384 MB

    if (ws_size >= needBig) {
        float* A = (float*)d_ws;
        float* B = A + BATCH * perAB;
        float* C = A;   // spatial C (64,294,294)/batch = 22.1 MB aliases dead A
        hipLaunchKernelGGL(k_qkv1x1, dim3(256, 3, BATCH),   dim3(256), 0, stream, x, qw, A);
        hipLaunchKernelGGL(k_dw3x3,  dim3(12288, 1, BATCH), dim3(256), 0, stream, A, dwv, B);
        hipLaunchKernelGGL(k_attn,   dim3(WCPB, 1, BATCH),  dim3(256), 0, stream, B, C);
        hipLaunchKernelGGL(k_proj,   dim3(512, 1, BATCH),   dim3(256), 0, stream, C, pw, out);
    } else {
        float* A = (float*)d_ws;
        float* B = A + perAB;
        float* C = A;
        for (int b = 0; b < BATCH; ++b) {
            const float* xb = x + (size_t)b * CIN * NPIX;
            float* ob = out + (size_t)b * CIN * NPIX;
            hipLaunchKernelGGL(k_qkv1x1, dim3(256, 3, 1),   dim3(256), 0, stream, xb, qw, A);
            hipLaunchKernelGGL(k_dw3x3,  dim3(12288, 1, 1), dim3(256), 0, stream, A, dwv, B);
            hipLaunchKernelGGL(k_attn,   dim3(WCPB, 1, 1),  dim3(256), 0, stream, B, C);
            hipLaunchKernelGGL(k_proj,   dim3(512, 1, 1),   dim3(256), 0, stream, C, pw, ob);
        }
    }
}